// Round 5
// baseline (534.522 us; speedup 1.0000x reference)
//
#include <hip/hip_runtime.h>
#include <hip/hip_bf16.h>
#include <cstddef>

#define RES 256
#define NCH 32
#define NPT 131072   // points per batch
#define NB  4

typedef _Float16 half8 __attribute__((ext_vector_type(8)));
typedef float    f32x4 __attribute__((ext_vector_type(4)));

#define H0_STRIDE 136   // fp16 elems per h0 row (128 + 8 pad, 16B-aligned rows)

// ---------------------------------------------------------------------------
// Transpose + fp16 convert: [bp][c][y][x] f32 -> [bp][y][x][c] f16.
// One block per (bp,y) row. float4 global loads, b128 LDS writes,
// broadcast LDS reads (bank = (4k+x')%32, 4-lane same-address broadcast).
// ---------------------------------------------------------------------------
__global__ __launch_bounds__(256) void transpose_fp16_kernel(
    const float* __restrict__ in, _Float16* __restrict__ out)
{
    __shared__ float tile[NCH][260];      // 260: multiple of 4 -> 16B-aligned rows
    const int bp = blockIdx.y;            // 0..11
    const int y  = blockIdx.x;            // 0..255
    const int t  = threadIdx.x;

    const float4* src4 = (const float4*)(in + (size_t)bp * NCH * RES * RES
                                            + (size_t)y * RES);
    const int lane4 = t & 63;             // float4 column 0..63
    const int cw    = t >> 6;             // 0..3
    #pragma unroll
    for (int i = 0; i < 8; ++i) {
        const int c = i * 4 + cw;
        const float4 v = src4[(size_t)c * (RES * RES / 4) + lane4];
        *(float4*)&tile[c][lane4 * 4] = v;
    }
    __syncthreads();

    _Float16* dst = out + ((size_t)bp * RES * RES + (size_t)y * RES) * NCH;
    #pragma unroll
    for (int i = 0; i < 4; ++i) {
        const int j  = i * 256 + t;       // 0..1023 half8-chunks
        const int x  = j >> 2;            // texel 0..255
        const int cg = j & 3;             // channel-group of 8
        half8 h;
        #pragma unroll
        for (int k = 0; k < 8; ++k)
            h[k] = (_Float16)tile[cg * 8 + k][x];
        *(half8*)&dst[(size_t)x * NCH + cg * 8] = h;   // 16B, coalesced 1KB/wave
    }
}

// ---------------------------------------------------------------------------
// Convert weights to fp16 with scaling: w0h = fp16(w0*16), w1h = fp16(w1).
// (feat scaled x256 at sampling; net h0 scale 4096, undone via w2/4096.)
// ---------------------------------------------------------------------------
__global__ __launch_bounds__(256) void prep_weights(
    const float* __restrict__ w0, const float* __restrict__ w1,
    _Float16* __restrict__ w0h, _Float16* __restrict__ w1h)
{
    const int i = blockIdx.x * 256 + threadIdx.x;   // grid 64*256 = 16384
    if (i < 128 * NCH) w0h[i] = (_Float16)(w0[i] * 16.0f);
    if (i < 128 * 128) w1h[i] = (_Float16)w1[i];
}

// ---------------------------------------------------------------------------
// Sampler: 2 threads per point (hf = channel half). No LDS; 8 waves/EU
// (VGPR=64 fits exactly) for deep memory-level parallelism on the 12
// independent corner loads. Writes feat fp16 (x256 scale) [point][32]
// with nontemporal stores (don't evict planes from L2).
// ---------------------------------------------------------------------------
__global__ __launch_bounds__(256, 8) void sample_kernel(
    const _Float16* __restrict__ planesT,   // [12][256][256][32] f16
    const float* __restrict__ coords,
    _Float16* __restrict__ featOut)         // [NB*NPT][32] f16
{
    const int gid = blockIdx.x * 256 + threadIdx.x;   // 0..2^20-1
    const int pt  = gid >> 1;
    const int hf  = gid & 1;
    const int b   = pt >> 17;                         // NPT = 2^17

    const float cx = coords[(size_t)pt * 3 + 0];
    const float cy = coords[(size_t)pt * 3 + 1];
    const float cz = coords[(size_t)pt * 3 + 2];

    float f[3][16];
    #pragma unroll
    for (int pl = 0; pl < 3; ++pl) {
        const float u = (pl == 0) ? cx : (pl == 1) ? cy : cx;
        const float v = (pl == 0) ? cy : cz;

        const float fx = (u + 1.0f) * 0.5f * (RES - 1);
        const float fy = (v + 1.0f) * 0.5f * (RES - 1);
        const float x0f = floorf(fx), y0f = floorf(fy);
        const float wx = fx - x0f, wy = fy - y0f;
        const int x0 = (int)x0f, y0 = (int)y0f;
        const bool vx1 = (x0 + 1) < RES;
        const bool vy1 = (y0 + 1) < RES;
        const int x1 = vx1 ? x0 + 1 : RES - 1;
        const int y1 = vy1 ? y0 + 1 : RES - 1;

        float w00 = (1.0f - wx) * (1.0f - wy);
        float w01 = wx * (1.0f - wy);
        float w10 = (1.0f - wx) * wy;
        float w11 = wx * wy;
        if (!vx1) { w01 = 0.0f; w11 = 0.0f; }
        if (!vy1) { w10 = 0.0f; w11 = 0.0f; }

        const _Float16* base = planesT
            + ((size_t)(b * 3 + pl) * RES * RES) * NCH + hf * 16;

        const half8* p00 = (const half8*)(base + (size_t)(y0 * RES + x0) * NCH);
        const half8* p01 = (const half8*)(base + (size_t)(y0 * RES + x1) * NCH);
        const half8* p10 = (const half8*)(base + (size_t)(y1 * RES + x0) * NCH);
        const half8* p11 = (const half8*)(base + (size_t)(y1 * RES + x1) * NCH);

        const half8 a00 = p00[0], b00 = p00[1];
        const half8 a01 = p01[0], b01 = p01[1];
        const half8 a10 = p10[0], b10 = p10[1];
        const half8 a11 = p11[0], b11 = p11[1];

        #pragma unroll
        for (int k = 0; k < 8; ++k) {
            f[pl][k] = fmaf((float)a11[k], w11, fmaf((float)a10[k], w10,
                       fmaf((float)a01[k], w01, (float)a00[k] * w00)));
            f[pl][8 + k] = fmaf((float)b11[k], w11, fmaf((float)b10[k], w10,
                           fmaf((float)b01[k], w01, (float)b00[k] * w00)));
        }
    }

    half8 o0, o1;
    #pragma unroll
    for (int k = 0; k < 8; ++k) {
        o0[k] = (_Float16)(f[0][k]     * f[1][k]     * f[2][k]     * 256.0f);
        o1[k] = (_Float16)(f[0][8 + k] * f[1][8 + k] * f[2][8 + k] * 256.0f);
    }
    _Float16* dst = featOut + (size_t)pt * NCH + hf * 16;
    __builtin_nontemporal_store(o0, (half8*)&dst[0]);
    __builtin_nontemporal_store(o1, (half8*)&dst[8]);
}

// ---------------------------------------------------------------------------
// GEMM: feat [Npts][32] f16 -> MLP 32->128->128->1 via MFMA 16x16x32 f16.
// Block = 128 points, 4 waves; each wave owns 32 points. LDS = h0LDS only.
// Register-pressure-aware: nt loops are DYNAMIC (unroll 1) and the layer-2
// epilogue is folded into the layer-1 nt loop, so only acc[2] (8 VGPRs) is
// live per iteration instead of acc1[2][8] (64) + 32 hoisted weight half8s.
// Layouts (verified m89/m120 + rounds 3/4):
//   A: lane holds A[m=lane&15][k=quad*8+j]
//   B: lane holds B[k=quad*8+j][n=lane&15] = W[n][k] row-major 8-contig
//   C/D: col n = lane&15, row m = quad*4+reg
// ---------------------------------------------------------------------------
__global__ __launch_bounds__(256, 4) void gemm_kernel(
    const _Float16* __restrict__ feat,    // [NB*NPT][32] f16 (x256)
    const _Float16* __restrict__ w0h,     // [128][32]  (x16)
    const _Float16* __restrict__ w1h,     // [128][128]
    const float* __restrict__ b0, const float* __restrict__ b1,
    const float* __restrict__ w2, const float* __restrict__ b2,
    float* __restrict__ out)
{
    __shared__ __align__(16) _Float16 h0LDS[4][32 * H0_STRIDE];   // 34.8 KB

    const int tid  = threadIdx.x;
    const int wv   = tid >> 6;
    const int lane = tid & 63;
    const int l15  = lane & 15;
    const int quad = lane >> 4;

    const int m0 = blockIdx.x * 128 + wv * 32;   // wave's first global point

    // ---- layer 0: A-frags straight from global feat
    half8 a0[2];
    #pragma unroll
    for (int mt = 0; mt < 2; ++mt)
        a0[mt] = *(const half8*)&feat[(size_t)(m0 + mt * 16 + l15) * NCH + quad * 8];

    #pragma unroll 1
    for (int nt = 0; nt < 8; ++nt) {
        const half8 bfr = *(const half8*)&w0h[(nt * 16 + l15) * NCH + quad * 8];
        const float b0g = b0[nt * 16 + l15] * 4096.0f;
        f32x4 acc[2];
        #pragma unroll
        for (int mt = 0; mt < 2; ++mt) {
            acc[mt] = (f32x4){0.f, 0.f, 0.f, 0.f};
            acc[mt] = __builtin_amdgcn_mfma_f32_16x16x32_f16(
                a0[mt], bfr, acc[mt], 0, 0, 0);
        }
        // bias + relu -> fp16 -> h0LDS (C-layout writes; A-layout reads)
        #pragma unroll
        for (int mt = 0; mt < 2; ++mt)
            #pragma unroll
            for (int r = 0; r < 4; ++r) {
                const float hval = fmaxf(acc[mt][r] + b0g, 0.0f);
                h0LDS[wv][(mt * 16 + quad * 4 + r) * H0_STRIDE + nt * 16 + l15]
                    = (_Float16)hval;
            }
    }

    // ---- layer 1 (+ fused layer-2 epilogue per nt)
    half8 a1[2][4];
    #pragma unroll
    for (int mt = 0; mt < 2; ++mt)
        #pragma unroll
        for (int ks = 0; ks < 4; ++ks)
            a1[mt][ks] = *(const half8*)
                &h0LDS[wv][(mt * 16 + l15) * H0_STRIDE + ks * 32 + quad * 8];

    float part[2][4];
    #pragma unroll
    for (int mt = 0; mt < 2; ++mt)
        #pragma unroll
        for (int r = 0; r < 4; ++r) part[mt][r] = 0.0f;

    #pragma unroll 1
    for (int nt = 0; nt < 8; ++nt) {
        const float b1g = b1[nt * 16 + l15] * 4096.0f;
        const float w2g = w2[nt * 16 + l15] * (1.0f / 4096.0f);
        f32x4 acc[2];
        #pragma unroll
        for (int mt = 0; mt < 2; ++mt) acc[mt] = (f32x4){0.f, 0.f, 0.f, 0.f};
        #pragma unroll
        for (int ks = 0; ks < 4; ++ks) {
            const half8 bfr = *(const half8*)
                &w1h[(nt * 16 + l15) * 128 + ks * 32 + quad * 8];
            #pragma unroll
            for (int mt = 0; mt < 2; ++mt)
                acc[mt] = __builtin_amdgcn_mfma_f32_16x16x32_f16(
                    a1[mt][ks], bfr, acc[mt], 0, 0, 0);
        }
        #pragma unroll
        for (int mt = 0; mt < 2; ++mt)
            #pragma unroll
            for (int r = 0; r < 4; ++r)
                part[mt][r] = fmaf(w2g, fmaxf(acc[mt][r] + b1g, 0.0f), part[mt][r]);
    }

    // reduce across the 16 lanes (l15) of each quad-group
    #pragma unroll
    for (int mt = 0; mt < 2; ++mt)
        #pragma unroll
        for (int r = 0; r < 4; ++r) {
            float s = part[mt][r];
            s += __shfl_xor(s, 1);
            s += __shfl_xor(s, 2);
            s += __shfl_xor(s, 4);
            s += __shfl_xor(s, 8);
            part[mt][r] = s;
        }

    if (l15 == 0) {
        const float bias2 = b2[0];
        #pragma unroll
        for (int mt = 0; mt < 2; ++mt)
            #pragma unroll
            for (int r = 0; r < 4; ++r)
                out[m0 + mt * 16 + quad * 4 + r] = part[mt][r] + bias2;
    }
}

// ---------------------------------------------------------------------------
// Fallback (ws too small): round-1 fused fp32 kernel on original layout.
// ---------------------------------------------------------------------------
__global__ __launch_bounds__(256) void fused_fallback(
    const float* __restrict__ planes, const float* __restrict__ coords,
    const float* __restrict__ w0, const float* __restrict__ b0,
    const float* __restrict__ w1, const float* __restrict__ b1,
    const float* __restrict__ w2, const float* __restrict__ b2,
    float* __restrict__ out)
{
    const int t = blockIdx.x * 256 + threadIdx.x;
    const int b = t >> 17;
    const float cx = coords[(size_t)t * 3 + 0];
    const float cy = coords[(size_t)t * 3 + 1];
    const float cz = coords[(size_t)t * 3 + 2];
    float feat[NCH];
    #pragma unroll
    for (int p = 0; p < 3; ++p) {
        const float u = (p == 0) ? cx : (p == 1) ? cy : cx;
        const float v = (p == 0) ? cy : cz;
        const float fx = (u + 1.0f) * 0.5f * (RES - 1);
        const float fy = (v + 1.0f) * 0.5f * (RES - 1);
        const float x0f = floorf(fx), y0f = floorf(fy);
        const float wx = fx - x0f, wy = fy - y0f;
        const int x0 = (int)x0f, y0 = (int)y0f;
        const bool vx1 = (x0 + 1) < RES, vy1 = (y0 + 1) < RES;
        const int x1 = vx1 ? x0 + 1 : RES - 1;
        const int y1 = vy1 ? y0 + 1 : RES - 1;
        float w00 = (1.0f - wx) * (1.0f - wy), w01 = wx * (1.0f - wy);
        float w10 = (1.0f - wx) * wy, w11 = wx * wy;
        if (!vx1) { w01 = 0.0f; w11 = 0.0f; }
        if (!vy1) { w10 = 0.0f; w11 = 0.0f; }
        const float* base = planes + (size_t)(b * 3 + p) * NCH * RES * RES;
        const float* p00 = base + (size_t)y0 * RES + x0;
        const float* p01 = base + (size_t)y0 * RES + x1;
        const float* p10 = base + (size_t)y1 * RES + x0;
        const float* p11 = base + (size_t)y1 * RES + x1;
        #pragma unroll
        for (int c = 0; c < NCH; ++c) {
            const size_t off = (size_t)c * RES * RES;
            float s = p00[off] * w00;
            s = fmaf(p01[off], w01, s);
            s = fmaf(p10[off], w10, s);
            s = fmaf(p11[off], w11, s);
            if (p == 0) feat[c] = s; else feat[c] *= s;
        }
    }
    float h0[128];
    #pragma unroll
    for (int g = 0; g < 128; ++g) {
        const float* wr = w0 + g * NCH;
        float aA = b0[g], aB = 0.0f;
        #pragma unroll
        for (int c = 0; c < NCH; c += 2) {
            aA = fmaf(wr[c], feat[c], aA);
            aB = fmaf(wr[c + 1], feat[c + 1], aB);
        }
        h0[g] = fmaxf(aA + aB, 0.0f);
    }
    float o = b2[0];
    for (int g = 0; g < 128; ++g) {
        const float* wr = w1 + g * 128;
        float aA = b1[g], aB = 0.0f, aC = 0.0f, aD = 0.0f;
        #pragma unroll
        for (int h = 0; h < 128; h += 4) {
            aA = fmaf(wr[h], h0[h], aA);
            aB = fmaf(wr[h + 1], h0[h + 1], aB);
            aC = fmaf(wr[h + 2], h0[h + 2], aC);
            aD = fmaf(wr[h + 3], h0[h + 3], aD);
        }
        o = fmaf(fmaxf((aA + aB) + (aC + aD), 0.0f), w2[g], o);
    }
    out[t] = o;
}

// ---------------------------------------------------------------------------
extern "C" void kernel_launch(void* const* d_in, const int* in_sizes, int n_in,
                              void* d_out, int out_size, void* d_ws, size_t ws_size,
                              hipStream_t stream)
{
    const float* trip   = (const float*)d_in[0];
    const float* coords = (const float*)d_in[1];
    const float* w0     = (const float*)d_in[2];
    const float* b0     = (const float*)d_in[3];
    const float* w1     = (const float*)d_in[4];
    const float* b1     = (const float*)d_in[5];
    const float* w2     = (const float*)d_in[6];
    const float* b2     = (const float*)d_in[7];
    float* out = (float*)d_out;

    const size_t planesTBytes = (size_t)NB * 3 * RES * RES * NCH * 2;   // 50331648
    const size_t w0hBytes  = 128 * NCH * 2;                             // 8192
    const size_t w1hBytes  = 128 * 128 * 2;                             // 32768
    const size_t featBytes = (size_t)NB * NPT * NCH * 2;                // 33554432
    const size_t needed = planesTBytes + w0hBytes + w1hBytes + featBytes;

    if (ws_size >= needed) {
        _Float16* planesT = (_Float16*)d_ws;
        _Float16* w0h     = (_Float16*)((char*)d_ws + planesTBytes);
        _Float16* w1h     = (_Float16*)((char*)d_ws + planesTBytes + w0hBytes);
        _Float16* featWS  = (_Float16*)((char*)d_ws + planesTBytes + w0hBytes + w1hBytes);

        transpose_fp16_kernel<<<dim3(RES, NB * 3), 256, 0, stream>>>(trip, planesT);
        prep_weights<<<64, 256, 0, stream>>>(w0, w1, w0h, w1h);
        sample_kernel<<<(NB * NPT * 2) / 256, 256, 0, stream>>>(planesT, coords, featWS);
        gemm_kernel<<<(NB * NPT) / 128, 256, 0, stream>>>(
            featWS, w0h, w1h, b0, b1, w2, b2, out);
    } else {
        fused_fallback<<<(NB * NPT) / 256, 256, 0, stream>>>(
            trip, coords, w0, b0, w1, b1, w2, b2, out);
    }
}

// Round 6
// 333.435 us; speedup vs baseline: 1.6031x; 1.6031x over previous
//
#include <hip/hip_runtime.h>
#include <hip/hip_bf16.h>
#include <cstddef>

#define RES 256
#define NCH 32
#define NPT 131072   // points per batch
#define NB  4

typedef _Float16 half8 __attribute__((ext_vector_type(8)));
typedef _Float16 half4 __attribute__((ext_vector_type(4)));
typedef float    f32x4 __attribute__((ext_vector_type(4)));

#define H0_STRIDE 136   // fp16 elems per h0 row (128 + 8 pad, 16B-aligned rows)

// ---------------------------------------------------------------------------
// Transpose + fp16 convert: [bp][c][y][x] f32 -> [bp][y][x][c] f16.
// v3: 2 rows per block, fp16 LDS tile (32 KB -> 5 blocks/CU).
// Phase 1: per c, 2 KB contiguous fp32 reads, convert, 8B LDS stores.
// Phase 2: per-texel gather, 2B/lane LDS reads (conflict-free), 16B stores.
// ---------------------------------------------------------------------------
__global__ __launch_bounds__(256) void transpose_fp16_kernel(
    const float* __restrict__ in, _Float16* __restrict__ out)
{
    __shared__ _Float16 tileh[NCH][2 * RES];   // 32 KB
    const int bp = blockIdx.y;                 // 0..11
    const int y2 = blockIdx.x;                 // 0..127 (pair of rows)
    const int t  = threadIdx.x;

    const float4* src4 = (const float4*)(in + (size_t)bp * NCH * RES * RES);
    const int f4l = t & 127;                   // float4 index within 2-row span
    const int chalf = t >> 7;                  // 0..1
    #pragma unroll
    for (int i = 0; i < 16; ++i) {
        const int c = i * 2 + chalf;
        const float4 v = src4[(size_t)c * (RES * RES / 4) + y2 * 128 + f4l];
        half4 h = { (_Float16)v.x, (_Float16)v.y, (_Float16)v.z, (_Float16)v.w };
        *(half4*)&tileh[c][f4l * 4] = h;
    }
    __syncthreads();

    _Float16* dst = out + ((size_t)bp * RES * RES + (size_t)y2 * 512) * NCH;
    #pragma unroll
    for (int rep = 0; rep < 2; ++rep) {
        const int x = rep * 256 + t;           // texel within the 2-row span
        #pragma unroll
        for (int cg = 0; cg < 4; ++cg) {
            half8 h;
            #pragma unroll
            for (int k = 0; k < 8; ++k)
                h[k] = tileh[cg * 8 + k][x];
            *(half8*)&dst[(size_t)x * NCH + cg * 8] = h;
        }
    }
}

// ---------------------------------------------------------------------------
// Convert weights to fp16 with scaling: w0h = fp16(w0*16), w1h = fp16(w1).
// (feat scaled x256 at sampling; net h0 scale 4096, undone via w2/4096.)
// ---------------------------------------------------------------------------
__global__ __launch_bounds__(256) void prep_weights(
    const float* __restrict__ w0, const float* __restrict__ w1,
    _Float16* __restrict__ w0h, _Float16* __restrict__ w1h)
{
    const int i = blockIdx.x * 256 + threadIdx.x;   // grid 64*256 = 16384
    if (i < 128 * NCH) w0h[i] = (_Float16)(w0[i] * 16.0f);
    if (i < 128 * 128) w1h[i] = (_Float16)w1[i];
}

// ---------------------------------------------------------------------------
// Sampler: 2 threads per point (hf = channel half). No LDS. launch_bounds
// (256,4): VGPR cap 64 == measured use, NO SPILL (R5 showed (256,8) caps
// VGPR at 32 -> 900 MB scratch spill; do not raise min-waves here).
// ---------------------------------------------------------------------------
__global__ __launch_bounds__(256, 4) void sample_kernel(
    const _Float16* __restrict__ planesT,   // [12][256][256][32] f16
    const float* __restrict__ coords,
    _Float16* __restrict__ featOut)         // [NB*NPT][32] f16
{
    const int gid = blockIdx.x * 256 + threadIdx.x;   // 0..2^20-1
    const int pt  = gid >> 1;
    const int hf  = gid & 1;
    const int b   = pt >> 17;                         // NPT = 2^17

    const float cx = coords[(size_t)pt * 3 + 0];
    const float cy = coords[(size_t)pt * 3 + 1];
    const float cz = coords[(size_t)pt * 3 + 2];

    float f[3][16];
    #pragma unroll
    for (int pl = 0; pl < 3; ++pl) {
        const float u = (pl == 0) ? cx : (pl == 1) ? cy : cx;
        const float v = (pl == 0) ? cy : cz;

        const float fx = (u + 1.0f) * 0.5f * (RES - 1);
        const float fy = (v + 1.0f) * 0.5f * (RES - 1);
        const float x0f = floorf(fx), y0f = floorf(fy);
        const float wx = fx - x0f, wy = fy - y0f;
        const int x0 = (int)x0f, y0 = (int)y0f;
        const bool vx1 = (x0 + 1) < RES;
        const bool vy1 = (y0 + 1) < RES;
        const int x1 = vx1 ? x0 + 1 : RES - 1;
        const int y1 = vy1 ? y0 + 1 : RES - 1;

        float w00 = (1.0f - wx) * (1.0f - wy);
        float w01 = wx * (1.0f - wy);
        float w10 = (1.0f - wx) * wy;
        float w11 = wx * wy;
        if (!vx1) { w01 = 0.0f; w11 = 0.0f; }
        if (!vy1) { w10 = 0.0f; w11 = 0.0f; }

        const _Float16* base = planesT
            + ((size_t)(b * 3 + pl) * RES * RES) * NCH + hf * 16;

        const half8* p00 = (const half8*)(base + (size_t)(y0 * RES + x0) * NCH);
        const half8* p01 = (const half8*)(base + (size_t)(y0 * RES + x1) * NCH);
        const half8* p10 = (const half8*)(base + (size_t)(y1 * RES + x0) * NCH);
        const half8* p11 = (const half8*)(base + (size_t)(y1 * RES + x1) * NCH);

        const half8 a00 = p00[0], b00 = p00[1];
        const half8 a01 = p01[0], b01 = p01[1];
        const half8 a10 = p10[0], b10 = p10[1];
        const half8 a11 = p11[0], b11 = p11[1];

        #pragma unroll
        for (int k = 0; k < 8; ++k) {
            f[pl][k] = fmaf((float)a11[k], w11, fmaf((float)a10[k], w10,
                       fmaf((float)a01[k], w01, (float)a00[k] * w00)));
            f[pl][8 + k] = fmaf((float)b11[k], w11, fmaf((float)b10[k], w10,
                           fmaf((float)b01[k], w01, (float)b00[k] * w00)));
        }
    }

    half8 o0, o1;
    #pragma unroll
    for (int k = 0; k < 8; ++k) {
        o0[k] = (_Float16)(f[0][k]     * f[1][k]     * f[2][k]     * 256.0f);
        o1[k] = (_Float16)(f[0][8 + k] * f[1][8 + k] * f[2][8 + k] * 256.0f);
    }
    _Float16* dst = featOut + (size_t)pt * NCH + hf * 16;
    *(half8*)&dst[0] = o0;
    *(half8*)&dst[8] = o1;
}

// ---------------------------------------------------------------------------
// GEMM: feat [Npts][32] f16 -> MLP 32->128->128->1 via MFMA 16x16x32 f16.
// Block = 128 points, 4 waves; each wave owns 32 points. LDS = h0LDS only.
// Register-lean: nt loops dynamic (unroll 1), layer-2 epilogue folded into
// the layer-1 nt loop so only acc[2] (8 VGPRs) is live per iteration.
// Layouts (verified m89/m120 + rounds 3/4):
//   A: lane holds A[m=lane&15][k=quad*8+j]
//   B: lane holds B[k=quad*8+j][n=lane&15] = W[n][k] row-major 8-contig
//   C/D: col n = lane&15, row m = quad*4+reg
// ---------------------------------------------------------------------------
__global__ __launch_bounds__(256, 4) void gemm_kernel(
    const _Float16* __restrict__ feat,    // [NB*NPT][32] f16 (x256)
    const _Float16* __restrict__ w0h,     // [128][32]  (x16)
    const _Float16* __restrict__ w1h,     // [128][128]
    const float* __restrict__ b0, const float* __restrict__ b1,
    const float* __restrict__ w2, const float* __restrict__ b2,
    float* __restrict__ out)
{
    __shared__ __align__(16) _Float16 h0LDS[4][32 * H0_STRIDE];   // 34.8 KB

    const int tid  = threadIdx.x;
    const int wv   = tid >> 6;
    const int lane = tid & 63;
    const int l15  = lane & 15;
    const int quad = lane >> 4;

    const int m0 = blockIdx.x * 128 + wv * 32;   // wave's first global point

    // ---- layer 0: A-frags straight from global feat
    half8 a0[2];
    #pragma unroll
    for (int mt = 0; mt < 2; ++mt)
        a0[mt] = *(const half8*)&feat[(size_t)(m0 + mt * 16 + l15) * NCH + quad * 8];

    #pragma unroll 1
    for (int nt = 0; nt < 8; ++nt) {
        const half8 bfr = *(const half8*)&w0h[(nt * 16 + l15) * NCH + quad * 8];
        const float b0g = b0[nt * 16 + l15] * 4096.0f;
        f32x4 acc[2];
        #pragma unroll
        for (int mt = 0; mt < 2; ++mt) {
            acc[mt] = (f32x4){0.f, 0.f, 0.f, 0.f};
            acc[mt] = __builtin_amdgcn_mfma_f32_16x16x32_f16(
                a0[mt], bfr, acc[mt], 0, 0, 0);
        }
        // bias + relu -> fp16 -> h0LDS (C-layout writes; A-layout reads)
        #pragma unroll
        for (int mt = 0; mt < 2; ++mt)
            #pragma unroll
            for (int r = 0; r < 4; ++r) {
                const float hval = fmaxf(acc[mt][r] + b0g, 0.0f);
                h0LDS[wv][(mt * 16 + quad * 4 + r) * H0_STRIDE + nt * 16 + l15]
                    = (_Float16)hval;
            }
    }

    // ---- layer 1 (+ fused layer-2 epilogue per nt)
    half8 a1[2][4];
    #pragma unroll
    for (int mt = 0; mt < 2; ++mt)
        #pragma unroll
        for (int ks = 0; ks < 4; ++ks)
            a1[mt][ks] = *(const half8*)
                &h0LDS[wv][(mt * 16 + l15) * H0_STRIDE + ks * 32 + quad * 8];

    float part[2][4];
    #pragma unroll
    for (int mt = 0; mt < 2; ++mt)
        #pragma unroll
        for (int r = 0; r < 4; ++r) part[mt][r] = 0.0f;

    #pragma unroll 1
    for (int nt = 0; nt < 8; ++nt) {
        const float b1g = b1[nt * 16 + l15] * 4096.0f;
        const float w2g = w2[nt * 16 + l15] * (1.0f / 4096.0f);
        f32x4 acc[2];
        #pragma unroll
        for (int mt = 0; mt < 2; ++mt) acc[mt] = (f32x4){0.f, 0.f, 0.f, 0.f};
        #pragma unroll
        for (int ks = 0; ks < 4; ++ks) {
            const half8 bfr = *(const half8*)
                &w1h[(nt * 16 + l15) * 128 + ks * 32 + quad * 8];
            #pragma unroll
            for (int mt = 0; mt < 2; ++mt)
                acc[mt] = __builtin_amdgcn_mfma_f32_16x16x32_f16(
                    a1[mt][ks], bfr, acc[mt], 0, 0, 0);
        }
        #pragma unroll
        for (int mt = 0; mt < 2; ++mt)
            #pragma unroll
            for (int r = 0; r < 4; ++r)
                part[mt][r] = fmaf(w2g, fmaxf(acc[mt][r] + b1g, 0.0f), part[mt][r]);
    }

    // reduce across the 16 lanes (l15) of each quad-group
    #pragma unroll
    for (int mt = 0; mt < 2; ++mt)
        #pragma unroll
        for (int r = 0; r < 4; ++r) {
            float s = part[mt][r];
            s += __shfl_xor(s, 1);
            s += __shfl_xor(s, 2);
            s += __shfl_xor(s, 4);
            s += __shfl_xor(s, 8);
            part[mt][r] = s;
        }

    if (l15 == 0) {
        const float bias2 = b2[0];
        #pragma unroll
        for (int mt = 0; mt < 2; ++mt)
            #pragma unroll
            for (int r = 0; r < 4; ++r)
                out[m0 + mt * 16 + quad * 4 + r] = part[mt][r] + bias2;
    }
}

// ---------------------------------------------------------------------------
// Fallback (ws too small): round-1 fused fp32 kernel on original layout.
// ---------------------------------------------------------------------------
__global__ __launch_bounds__(256) void fused_fallback(
    const float* __restrict__ planes, const float* __restrict__ coords,
    const float* __restrict__ w0, const float* __restrict__ b0,
    const float* __restrict__ w1, const float* __restrict__ b1,
    const float* __restrict__ w2, const float* __restrict__ b2,
    float* __restrict__ out)
{
    const int t = blockIdx.x * 256 + threadIdx.x;
    const int b = t >> 17;
    const float cx = coords[(size_t)t * 3 + 0];
    const float cy = coords[(size_t)t * 3 + 1];
    const float cz = coords[(size_t)t * 3 + 2];
    float feat[NCH];
    #pragma unroll
    for (int p = 0; p < 3; ++p) {
        const float u = (p == 0) ? cx : (p == 1) ? cy : cx;
        const float v = (p == 0) ? cy : cz;
        const float fx = (u + 1.0f) * 0.5f * (RES - 1);
        const float fy = (v + 1.0f) * 0.5f * (RES - 1);
        const float x0f = floorf(fx), y0f = floorf(fy);
        const float wx = fx - x0f, wy = fy - y0f;
        const int x0 = (int)x0f, y0 = (int)y0f;
        const bool vx1 = (x0 + 1) < RES, vy1 = (y0 + 1) < RES;
        const int x1 = vx1 ? x0 + 1 : RES - 1;
        const int y1 = vy1 ? y0 + 1 : RES - 1;
        float w00 = (1.0f - wx) * (1.0f - wy), w01 = wx * (1.0f - wy);
        float w10 = (1.0f - wx) * wy, w11 = wx * wy;
        if (!vx1) { w01 = 0.0f; w11 = 0.0f; }
        if (!vy1) { w10 = 0.0f; w11 = 0.0f; }
        const float* base = planes + (size_t)(b * 3 + p) * NCH * RES * RES;
        const float* p00 = base + (size_t)y0 * RES + x0;
        const float* p01 = base + (size_t)y0 * RES + x1;
        const float* p10 = base + (size_t)y1 * RES + x0;
        const float* p11 = base + (size_t)y1 * RES + x1;
        #pragma unroll
        for (int c = 0; c < NCH; ++c) {
            const size_t off = (size_t)c * RES * RES;
            float s = p00[off] * w00;
            s = fmaf(p01[off], w01, s);
            s = fmaf(p10[off], w10, s);
            s = fmaf(p11[off], w11, s);
            if (p == 0) feat[c] = s; else feat[c] *= s;
        }
    }
    float h0[128];
    #pragma unroll
    for (int g = 0; g < 128; ++g) {
        const float* wr = w0 + g * NCH;
        float aA = b0[g], aB = 0.0f;
        #pragma unroll
        for (int c = 0; c < NCH; c += 2) {
            aA = fmaf(wr[c], feat[c], aA);
            aB = fmaf(wr[c + 1], feat[c + 1], aB);
        }
        h0[g] = fmaxf(aA + aB, 0.0f);
    }
    float o = b2[0];
    for (int g = 0; g < 128; ++g) {
        const float* wr = w1 + g * 128;
        float aA = b1[g], aB = 0.0f, aC = 0.0f, aD = 0.0f;
        #pragma unroll
        for (int h = 0; h < 128; h += 4) {
            aA = fmaf(wr[h], h0[h], aA);
            aB = fmaf(wr[h + 1], h0[h + 1], aB);
            aC = fmaf(wr[h + 2], h0[h + 2], aC);
            aD = fmaf(wr[h + 3], h0[h + 3], aD);
        }
        o = fmaf(fmaxf((aA + aB) + (aC + aD), 0.0f), w2[g], o);
    }
    out[t] = o;
}

// ---------------------------------------------------------------------------
extern "C" void kernel_launch(void* const* d_in, const int* in_sizes, int n_in,
                              void* d_out, int out_size, void* d_ws, size_t ws_size,
                              hipStream_t stream)
{
    const float* trip   = (const float*)d_in[0];
    const float* coords = (const float*)d_in[1];
    const float* w0     = (const float*)d_in[2];
    const float* b0     = (const float*)d_in[3];
    const float* w1     = (const float*)d_in[4];
    const float* b1     = (const float*)d_in[5];
    const float* w2     = (const float*)d_in[6];
    const float* b2     = (const float*)d_in[7];
    float* out = (float*)d_out;

    const size_t planesTBytes = (size_t)NB * 3 * RES * RES * NCH * 2;   // 50331648
    const size_t w0hBytes  = 128 * NCH * 2;                             // 8192
    const size_t w1hBytes  = 128 * 128 * 2;                             // 32768
    const size_t featBytes = (size_t)NB * NPT * NCH * 2;                // 33554432
    const size_t needed = planesTBytes + w0hBytes + w1hBytes + featBytes;

    if (ws_size >= needed) {
        _Float16* planesT = (_Float16*)d_ws;
        _Float16* w0h     = (_Float16*)((char*)d_ws + planesTBytes);
        _Float16* w1h     = (_Float16*)((char*)d_ws + planesTBytes + w0hBytes);
        _Float16* featWS  = (_Float16*)((char*)d_ws + planesTBytes + w0hBytes + w1hBytes);

        transpose_fp16_kernel<<<dim3(RES / 2, NB * 3), 256, 0, stream>>>(trip, planesT);
        prep_weights<<<64, 256, 0, stream>>>(w0, w1, w0h, w1h);
        sample_kernel<<<(NB * NPT * 2) / 256, 256, 0, stream>>>(planesT, coords, featWS);
        gemm_kernel<<<(NB * NPT) / 128, 256, 0, stream>>>(
            featWS, w0h, w1h, b0, b1, w2, b2, out);
    } else {
        fused_fallback<<<(NB * NPT) / 256, 256, 0, stream>>>(
            trip, coords, w0, b0, w1, b1, w2, b2, out);
    }
}

// Round 7
// 300.849 us; speedup vs baseline: 1.7767x; 1.1083x over previous
//
#include <hip/hip_runtime.h>
#include <hip/hip_bf16.h>
#include <cstddef>

#define RES 256
#define NCH 32
#define NPT 131072   // points per batch
#define NB  4

typedef _Float16 half8 __attribute__((ext_vector_type(8)));
typedef _Float16 half4 __attribute__((ext_vector_type(4)));
typedef float    f32x4 __attribute__((ext_vector_type(4)));

#define FEAT_STRIDE 40    // halves per feat row (32+8 pad, 80B rows, 16B-aligned)
#define H0_STRIDE   136   // halves per h0 row (128+8 pad, 272B rows, 16B-aligned)

// ---------------------------------------------------------------------------
// Transpose + fp16 convert: [bp][c][y][x] f32 -> [bp][y][x][c] f16.
// v4: 1 row/block (3072 blocks, 16.5 KB LDS -> 9 blocks/CU).
// ---------------------------------------------------------------------------
__global__ __launch_bounds__(256) void transpose_fp16_kernel(
    const float* __restrict__ in, _Float16* __restrict__ out)
{
    __shared__ _Float16 tileh[NCH][RES + 8];   // 16.5 KB
    const int bp = blockIdx.y;                 // 0..11
    const int y  = blockIdx.x;                 // 0..255
    const int t  = threadIdx.x;

    const float4* src4 = (const float4*)(in + (size_t)bp * NCH * RES * RES);
    const int lane64 = t & 63;
    const int cq     = t >> 6;                 // 0..3
    #pragma unroll
    for (int i = 0; i < 8; ++i) {
        const int c = cq * 8 + i;
        const float4 v = src4[(size_t)c * (RES * RES / 4) + y * (RES / 4) + lane64];
        half4 h = { (_Float16)v.x, (_Float16)v.y, (_Float16)v.z, (_Float16)v.w };
        *(half4*)&tileh[c][lane64 * 4] = h;
    }
    __syncthreads();

    _Float16* dst = out + ((size_t)bp * RES * RES + (size_t)y * RES) * NCH;
    const int x = t;                           // texel 0..255
    #pragma unroll
    for (int cg = 0; cg < 4; ++cg) {
        half8 h;
        #pragma unroll
        for (int k = 0; k < 8; ++k)
            h[k] = tileh[cg * 8 + k][x];
        *(half8*)&dst[(size_t)x * NCH + cg * 8] = h;
    }
}

// ---------------------------------------------------------------------------
// Convert weights to fp16 with scaling: w0h = fp16(w0*16), w1h = fp16(w1).
// (feat scaled x256 at sampling; net h0 scale 4096, undone via w2/4096.)
// ---------------------------------------------------------------------------
__global__ __launch_bounds__(256) void prep_weights(
    const float* __restrict__ w0, const float* __restrict__ w1,
    _Float16* __restrict__ w0h, _Float16* __restrict__ w1h)
{
    const int i = blockIdx.x * 256 + threadIdx.x;   // grid 64*256 = 16384
    if (i < 128 * NCH) w0h[i] = (_Float16)(w0[i] * 16.0f);
    if (i < 128 * 128) w1h[i] = (_Float16)w1[i];
}

// ---------------------------------------------------------------------------
// Fused sample + MFMA MLP. Block = 128 points, 4 waves; wave wv owns points
// wv*32..wv*32+31 end-to-end. feat LDS (10 KB) is ALIASED over h0LDS
// (34.8 KB): each wave's a0 reads touch only rows written by its own threads
// (row p written by tids 2p,2p+1 == wave p/32), so the single __syncthreads
// after the a0 loads is the only barrier needed before h0 clobbers feat.
// launch_bounds(256,2): VGPR cap 128 (R5: cap = 256/min_waves; phase-B ~120).
// MFMA 16x16x32 f16 layouts (verified m89/m120 + rounds 3/4/6):
//   A: lane holds A[m=lane&15][k=quad*8+j]
//   B: lane holds B[k=quad*8+j][n=lane&15] = W[n][k] row-major 8-contig
//   C/D: col n = lane&15, row m = quad*4+reg
// ---------------------------------------------------------------------------
__global__ __launch_bounds__(256, 2) void fused_kernel(
    const _Float16* __restrict__ planesT,   // [12][256][256][32] f16
    const float* __restrict__ coords,
    const _Float16* __restrict__ w0h,       // [128][32]  (x16)
    const _Float16* __restrict__ w1h,       // [128][128]
    const float* __restrict__ b0, const float* __restrict__ b1,
    const float* __restrict__ w2, const float* __restrict__ b2,
    float* __restrict__ out)
{
    __shared__ __align__(16) _Float16 smem[4 * 32 * H0_STRIDE];   // 34.8 KB
    _Float16* featLDS = smem;   // 128*FEAT_STRIDE = 5120 halves (aliased)
    _Float16* h0LDS   = smem;   // 4 wave-private 32x136 regions

    const int tid  = threadIdx.x;
    const int wv   = tid >> 6;
    const int lane = tid & 63;
    const int l15  = lane & 15;
    const int quad = lane >> 4;

    // ================= phase A: bilinear sample, 2 threads/point ===========
    {
        const int p  = tid >> 1;                    // block-local point 0..127
        const int hf = tid & 1;                     // channel half
        const int gp = blockIdx.x * 128 + p;
        const int b  = gp >> 17;                    // NPT = 2^17
        const float cx = coords[(size_t)gp * 3 + 0];
        const float cy = coords[(size_t)gp * 3 + 1];
        const float cz = coords[(size_t)gp * 3 + 2];

        float f[3][16];
        #pragma unroll
        for (int pl = 0; pl < 3; ++pl) {
            const float u = (pl == 0) ? cx : (pl == 1) ? cy : cx;
            const float v = (pl == 0) ? cy : cz;

            const float fx = (u + 1.0f) * 0.5f * (RES - 1);
            const float fy = (v + 1.0f) * 0.5f * (RES - 1);
            const float x0f = floorf(fx), y0f = floorf(fy);
            const float wx = fx - x0f, wy = fy - y0f;
            const int x0 = (int)x0f, y0 = (int)y0f;
            const bool vx1 = (x0 + 1) < RES;
            const bool vy1 = (y0 + 1) < RES;
            const int x1 = vx1 ? x0 + 1 : RES - 1;
            const int y1 = vy1 ? y0 + 1 : RES - 1;

            float w00 = (1.0f - wx) * (1.0f - wy);
            float w01 = wx * (1.0f - wy);
            float w10 = (1.0f - wx) * wy;
            float w11 = wx * wy;
            if (!vx1) { w01 = 0.0f; w11 = 0.0f; }
            if (!vy1) { w10 = 0.0f; w11 = 0.0f; }

            const _Float16* base = planesT
                + ((size_t)(b * 3 + pl) * RES * RES) * NCH + hf * 16;

            const half8* p00 = (const half8*)(base + (size_t)(y0 * RES + x0) * NCH);
            const half8* p01 = (const half8*)(base + (size_t)(y0 * RES + x1) * NCH);
            const half8* p10 = (const half8*)(base + (size_t)(y1 * RES + x0) * NCH);
            const half8* p11 = (const half8*)(base + (size_t)(y1 * RES + x1) * NCH);

            const half8 a00 = p00[0], b00 = p00[1];
            const half8 a01 = p01[0], b01 = p01[1];
            const half8 a10 = p10[0], b10 = p10[1];
            const half8 a11 = p11[0], b11 = p11[1];

            #pragma unroll
            for (int k = 0; k < 8; ++k) {
                f[pl][k] = fmaf((float)a11[k], w11, fmaf((float)a10[k], w10,
                           fmaf((float)a01[k], w01, (float)a00[k] * w00)));
                f[pl][8 + k] = fmaf((float)b11[k], w11, fmaf((float)b10[k], w10,
                               fmaf((float)b01[k], w01, (float)b00[k] * w00)));
            }
        }
        half8 o0, o1;
        #pragma unroll
        for (int k = 0; k < 8; ++k) {
            o0[k] = (_Float16)(f[0][k]     * f[1][k]     * f[2][k]     * 256.0f);
            o1[k] = (_Float16)(f[0][8 + k] * f[1][8 + k] * f[2][8 + k] * 256.0f);
        }
        *(half8*)&featLDS[p * FEAT_STRIDE + hf * 16 + 0] = o0;
        *(half8*)&featLDS[p * FEAT_STRIDE + hf * 16 + 8] = o1;
    }
    // No barrier: wave wv reads a0 only from rows p = wv*32..wv*32+31,
    // which were written by tids 2p..2p+1 -- i.e. wave wv itself.

    const int m0l = wv * 32;

    half8 a0[2];
    #pragma unroll
    for (int mt = 0; mt < 2; ++mt)
        a0[mt] = *(const half8*)&featLDS[(m0l + mt * 16 + l15) * FEAT_STRIDE + quad * 8];

    __syncthreads();   // all a0 loaded before h0 writes clobber featLDS

    // preload per-lane bias/weight scalars (latency hidden behind phase A tail)
    float b0v[8], b1v[8], w2s[8];
    #pragma unroll
    for (int nt = 0; nt < 8; ++nt) {
        b0v[nt] = b0[nt * 16 + l15] * 4096.0f;
        b1v[nt] = b1[nt * 16 + l15] * 4096.0f;
        w2s[nt] = w2[nt * 16 + l15] * (1.0f / 4096.0f);
    }

    _Float16* h0w = h0LDS + wv * 32 * H0_STRIDE;   // wave-private region

    // ================= layer 0 =============================================
    #pragma unroll 1
    for (int nt = 0; nt < 8; ++nt) {
        const half8 bfr = *(const half8*)&w0h[(nt * 16 + l15) * NCH + quad * 8];
        f32x4 acc[2];
        #pragma unroll
        for (int mt = 0; mt < 2; ++mt) {
            acc[mt] = (f32x4){0.f, 0.f, 0.f, 0.f};
            acc[mt] = __builtin_amdgcn_mfma_f32_16x16x32_f16(
                a0[mt], bfr, acc[mt], 0, 0, 0);
        }
        #pragma unroll
        for (int mt = 0; mt < 2; ++mt)
            #pragma unroll
            for (int r = 0; r < 4; ++r) {
                const float hval = fmaxf(acc[mt][r] + b0v[nt], 0.0f);
                h0w[(mt * 16 + quad * 4 + r) * H0_STRIDE + nt * 16 + l15]
                    = (_Float16)hval;
            }
    }

    // ================= layer 1 (+ fused layer-2 epilogue) ==================
    half8 a1[2][4];
    #pragma unroll
    for (int mt = 0; mt < 2; ++mt)
        #pragma unroll
        for (int ks = 0; ks < 4; ++ks)
            a1[mt][ks] = *(const half8*)
                &h0w[(mt * 16 + l15) * H0_STRIDE + ks * 32 + quad * 8];

    float part[2][4];
    #pragma unroll
    for (int mt = 0; mt < 2; ++mt)
        #pragma unroll
        for (int r = 0; r < 4; ++r) part[mt][r] = 0.0f;

    #pragma unroll 1
    for (int nt = 0; nt < 8; ++nt) {
        f32x4 acc[2];
        #pragma unroll
        for (int mt = 0; mt < 2; ++mt) acc[mt] = (f32x4){0.f, 0.f, 0.f, 0.f};
        #pragma unroll
        for (int ks = 0; ks < 4; ++ks) {
            const half8 bfr = *(const half8*)
                &w1h[(nt * 16 + l15) * 128 + ks * 32 + quad * 8];
            #pragma unroll
            for (int mt = 0; mt < 2; ++mt)
                acc[mt] = __builtin_amdgcn_mfma_f32_16x16x32_f16(
                    a1[mt][ks], bfr, acc[mt], 0, 0, 0);
        }
        #pragma unroll
        for (int mt = 0; mt < 2; ++mt)
            #pragma unroll
            for (int r = 0; r < 4; ++r)
                part[mt][r] = fmaf(w2s[nt], fmaxf(acc[mt][r] + b1v[nt], 0.0f),
                                   part[mt][r]);
    }

    // reduce across the 16 lanes (l15) of each quad-group
    #pragma unroll
    for (int mt = 0; mt < 2; ++mt)
        #pragma unroll
        for (int r = 0; r < 4; ++r) {
            float s = part[mt][r];
            s += __shfl_xor(s, 1);
            s += __shfl_xor(s, 2);
            s += __shfl_xor(s, 4);
            s += __shfl_xor(s, 8);
            part[mt][r] = s;
        }

    if (l15 == 0) {
        const float bias2 = b2[0];
        const int base = blockIdx.x * 128 + m0l;
        #pragma unroll
        for (int mt = 0; mt < 2; ++mt)
            #pragma unroll
            for (int r = 0; r < 4; ++r)
                out[base + mt * 16 + quad * 4 + r] = part[mt][r] + bias2;
    }
}

// ---------------------------------------------------------------------------
// Fallback (ws too small): round-1 fused fp32 kernel on original layout.
// ---------------------------------------------------------------------------
__global__ __launch_bounds__(256) void fused_fallback(
    const float* __restrict__ planes, const float* __restrict__ coords,
    const float* __restrict__ w0, const float* __restrict__ b0,
    const float* __restrict__ w1, const float* __restrict__ b1,
    const float* __restrict__ w2, const float* __restrict__ b2,
    float* __restrict__ out)
{
    const int t = blockIdx.x * 256 + threadIdx.x;
    const int b = t >> 17;
    const float cx = coords[(size_t)t * 3 + 0];
    const float cy = coords[(size_t)t * 3 + 1];
    const float cz = coords[(size_t)t * 3 + 2];
    float feat[NCH];
    #pragma unroll
    for (int p = 0; p < 3; ++p) {
        const float u = (p == 0) ? cx : (p == 1) ? cy : cx;
        const float v = (p == 0) ? cy : cz;
        const float fx = (u + 1.0f) * 0.5f * (RES - 1);
        const float fy = (v + 1.0f) * 0.5f * (RES - 1);
        const float x0f = floorf(fx), y0f = floorf(fy);
        const float wx = fx - x0f, wy = fy - y0f;
        const int x0 = (int)x0f, y0 = (int)y0f;
        const bool vx1 = (x0 + 1) < RES, vy1 = (y0 + 1) < RES;
        const int x1 = vx1 ? x0 + 1 : RES - 1;
        const int y1 = vy1 ? y0 + 1 : RES - 1;
        float w00 = (1.0f - wx) * (1.0f - wy), w01 = wx * (1.0f - wy);
        float w10 = (1.0f - wx) * wy, w11 = wx * wy;
        if (!vx1) { w01 = 0.0f; w11 = 0.0f; }
        if (!vy1) { w10 = 0.0f; w11 = 0.0f; }
        const float* base = planes + (size_t)(b * 3 + p) * NCH * RES * RES;
        const float* p00 = base + (size_t)y0 * RES + x0;
        const float* p01 = base + (size_t)y0 * RES + x1;
        const float* p10 = base + (size_t)y1 * RES + x0;
        const float* p11 = base + (size_t)y1 * RES + x1;
        #pragma unroll
        for (int c = 0; c < NCH; ++c) {
            const size_t off = (size_t)c * RES * RES;
            float s = p00[off] * w00;
            s = fmaf(p01[off], w01, s);
            s = fmaf(p10[off], w10, s);
            s = fmaf(p11[off], w11, s);
            if (p == 0) feat[c] = s; else feat[c] *= s;
        }
    }
    float h0[128];
    #pragma unroll
    for (int g = 0; g < 128; ++g) {
        const float* wr = w0 + g * NCH;
        float aA = b0[g], aB = 0.0f;
        #pragma unroll
        for (int c = 0; c < NCH; c += 2) {
            aA = fmaf(wr[c], feat[c], aA);
            aB = fmaf(wr[c + 1], feat[c + 1], aB);
        }
        h0[g] = fmaxf(aA + aB, 0.0f);
    }
    float o = b2[0];
    for (int g = 0; g < 128; ++g) {
        const float* wr = w1 + g * 128;
        float aA = b1[g], aB = 0.0f, aC = 0.0f, aD = 0.0f;
        #pragma unroll
        for (int h = 0; h < 128; h += 4) {
            aA = fmaf(wr[h], h0[h], aA);
            aB = fmaf(wr[h + 1], h0[h + 1], aB);
            aC = fmaf(wr[h + 2], h0[h + 2], aC);
            aD = fmaf(wr[h + 3], h0[h + 3], aD);
        }
        o = fmaf(fmaxf((aA + aB) + (aC + aD), 0.0f), w2[g], o);
    }
    out[t] = o;
}

// ---------------------------------------------------------------------------
extern "C" void kernel_launch(void* const* d_in, const int* in_sizes, int n_in,
                              void* d_out, int out_size, void* d_ws, size_t ws_size,
                              hipStream_t stream)
{
    const float* trip   = (const float*)d_in[0];
    const float* coords = (const float*)d_in[1];
    const float* w0     = (const float*)d_in[2];
    const float* b0     = (const float*)d_in[3];
    const float* w1     = (const float*)d_in[4];
    const float* b1     = (const float*)d_in[5];
    const float* w2     = (const float*)d_in[6];
    const float* b2     = (const float*)d_in[7];
    float* out = (float*)d_out;

    const size_t planesTBytes = (size_t)NB * 3 * RES * RES * NCH * 2;   // 50331648
    const size_t w0hBytes = 128 * NCH * 2;                              // 8192
    const size_t w1hBytes = 128 * 128 * 2;                              // 32768
    const size_t needed = planesTBytes + w0hBytes + w1hBytes;

    if (ws_size >= needed) {
        _Float16* planesT = (_Float16*)d_ws;
        _Float16* w0h     = (_Float16*)((char*)d_ws + planesTBytes);
        _Float16* w1h     = (_Float16*)((char*)d_ws + planesTBytes + w0hBytes);

        transpose_fp16_kernel<<<dim3(RES, NB * 3), 256, 0, stream>>>(trip, planesT);
        prep_weights<<<64, 256, 0, stream>>>(w0, w1, w0h, w1h);
        fused_kernel<<<(NB * NPT) / 128, 256, 0, stream>>>(
            planesT, coords, w0h, w1h, b0, b1, w2, b2, out);
    } else {
        fused_fallback<<<(NB * NPT) / 256, 256, 0, stream>>>(
            trip, coords, w0, b0, w1, b1, w2, b2, out);
    }
}

// Round 8
// 296.239 us; speedup vs baseline: 1.8044x; 1.0156x over previous
//
#include <hip/hip_runtime.h>
#include <hip/hip_bf16.h>
#include <cstddef>

#define RES 256
#define NCH 32
#define NPT 131072   // points per batch
#define NB  4

typedef _Float16 half8 __attribute__((ext_vector_type(8)));
typedef _Float16 half4 __attribute__((ext_vector_type(4)));
typedef float    f32x4 __attribute__((ext_vector_type(4)));

#define FEAT_STRIDE 40    // halves per feat row (32+8 pad, 80B rows, 16B-aligned)
#define H0_STRIDE   136   // halves per h0 row (128+8 pad, 272B rows, 16B-aligned)
#define WAVE_LDS    (32 * H0_STRIDE)   // halves per wave-private region

// ---------------------------------------------------------------------------
// Transpose + fp16 convert + weight prep, one kernel.
// bp 0..11: [bp][c][y][x] f32 -> [bp][y][x][c] f16 (1 row/block).
// bp == 12: convert w0/w1 to fp16 with scaling (w0h = w0*16, w1h = w1).
// (feat scaled x256 at sampling; net h0 scale 4096, undone via w2/4096.)
// ---------------------------------------------------------------------------
__global__ __launch_bounds__(256) void transpose_prep_kernel(
    const float* __restrict__ in,
    const float* __restrict__ w0, const float* __restrict__ w1,
    _Float16* __restrict__ out,
    _Float16* __restrict__ w0h, _Float16* __restrict__ w1h)
{
    const int bp = blockIdx.y;                 // 0..12
    const int t  = threadIdx.x;

    if (bp == 12) {                            // weight-prep blocks
        const int i = blockIdx.x * 256 + t;    // need 20480 threads of 65536
        if (i < 128 * NCH)  w0h[i] = (_Float16)(w0[i] * 16.0f);
        if (i < 128 * 128)  w1h[i] = (_Float16)w1[i];
        return;
    }

    __shared__ _Float16 tileh[NCH][RES + 8];   // 16.5 KB
    const int y = blockIdx.x;                  // 0..255

    const float4* src4 = (const float4*)(in + (size_t)bp * NCH * RES * RES);
    const int lane64 = t & 63;
    const int cq     = t >> 6;                 // 0..3
    #pragma unroll
    for (int i = 0; i < 8; ++i) {
        const int c = cq * 8 + i;
        const float4 v = src4[(size_t)c * (RES * RES / 4) + y * (RES / 4) + lane64];
        half4 h = { (_Float16)v.x, (_Float16)v.y, (_Float16)v.z, (_Float16)v.w };
        *(half4*)&tileh[c][lane64 * 4] = h;
    }
    __syncthreads();

    _Float16* dst = out + ((size_t)bp * RES * RES + (size_t)y * RES) * NCH;
    const int x = t;                           // texel 0..255
    #pragma unroll
    for (int cg = 0; cg < 4; ++cg) {
        half8 h;
        #pragma unroll
        for (int k = 0; k < 8; ++k)
            h[k] = tileh[cg * 8 + k][x];
        *(half8*)&dst[(size_t)x * NCH + cg * 8] = h;
    }
}

// ---------------------------------------------------------------------------
// Fused sample + MFMA MLP, ZERO barriers. Block = 128 points, 4 waves; wave
// wv owns points wv*32..wv*32+31 end-to-end and a wave-private LDS region
// (feat rows aliased into the low 2.5 KB of the wave's 8.7 KB h0 region).
// All LDS dependencies are within-wave; compiler-inserted lgkmcnt waits
// order the may-aliasing ds_write/ds_read pairs (proven by R7's barrierless
// h0->a1 path). No __syncthreads -> no drain points; waves decouple fully.
// launch_bounds(256,2): VGPR cap 128 (measured rule: cap = 256/min_waves).
// MFMA 16x16x32 f16 layouts (verified m89/m120 + rounds 3/4/6/7):
//   A: lane holds A[m=lane&15][k=quad*8+j]
//   B: lane holds B[k=quad*8+j][n=lane&15] = W[n][k] row-major 8-contig
//   C/D: col n = lane&15, row m = quad*4+reg
// ---------------------------------------------------------------------------
__global__ __launch_bounds__(256, 2) void fused_kernel(
    const _Float16* __restrict__ planesT,   // [12][256][256][32] f16
    const float* __restrict__ coords,
    const _Float16* __restrict__ w0h,       // [128][32]  (x16)
    const _Float16* __restrict__ w1h,       // [128][128]
    const float* __restrict__ b0, const float* __restrict__ b1,
    const float* __restrict__ w2, const float* __restrict__ b2,
    float* __restrict__ out)
{
    __shared__ __align__(16) _Float16 smem[4 * WAVE_LDS];   // 34.8 KB

    const int tid  = threadIdx.x;
    const int wv   = tid >> 6;
    const int lane = tid & 63;
    const int l15  = lane & 15;
    const int quad = lane >> 4;

    _Float16* wbase = smem + wv * WAVE_LDS;   // this wave's private region

    // ================= phase A: bilinear sample, 2 threads/point ===========
    {
        const int p  = tid >> 1;                    // block-local point 0..127
        const int pl_ = p & 31;                     // wave-local point 0..31
        const int hf = tid & 1;                     // channel half
        const int gp = blockIdx.x * 128 + p;
        const int b  = gp >> 17;                    // NPT = 2^17
        const float cx = coords[(size_t)gp * 3 + 0];
        const float cy = coords[(size_t)gp * 3 + 1];
        const float cz = coords[(size_t)gp * 3 + 2];

        float f[3][16];
        #pragma unroll
        for (int pl = 0; pl < 3; ++pl) {
            const float u = (pl == 0) ? cx : (pl == 1) ? cy : cx;
            const float v = (pl == 0) ? cy : cz;

            const float fx = (u + 1.0f) * 0.5f * (RES - 1);
            const float fy = (v + 1.0f) * 0.5f * (RES - 1);
            const float x0f = floorf(fx), y0f = floorf(fy);
            const float wx = fx - x0f, wy = fy - y0f;
            const int x0 = (int)x0f, y0 = (int)y0f;
            const bool vx1 = (x0 + 1) < RES;
            const bool vy1 = (y0 + 1) < RES;
            const int x1 = vx1 ? x0 + 1 : RES - 1;
            const int y1 = vy1 ? y0 + 1 : RES - 1;

            float w00 = (1.0f - wx) * (1.0f - wy);
            float w01 = wx * (1.0f - wy);
            float w10 = (1.0f - wx) * wy;
            float w11 = wx * wy;
            if (!vx1) { w01 = 0.0f; w11 = 0.0f; }
            if (!vy1) { w10 = 0.0f; w11 = 0.0f; }

            const _Float16* base = planesT
                + ((size_t)(b * 3 + pl) * RES * RES) * NCH + hf * 16;

            const half8* p00 = (const half8*)(base + (size_t)(y0 * RES + x0) * NCH);
            const half8* p01 = (const half8*)(base + (size_t)(y0 * RES + x1) * NCH);
            const half8* p10 = (const half8*)(base + (size_t)(y1 * RES + x0) * NCH);
            const half8* p11 = (const half8*)(base + (size_t)(y1 * RES + x1) * NCH);

            const half8 a00 = p00[0], b00 = p00[1];
            const half8 a01 = p01[0], b01 = p01[1];
            const half8 a10 = p10[0], b10 = p10[1];
            const half8 a11 = p11[0], b11 = p11[1];

            #pragma unroll
            for (int k = 0; k < 8; ++k) {
                f[pl][k] = fmaf((float)a11[k], w11, fmaf((float)a10[k], w10,
                           fmaf((float)a01[k], w01, (float)a00[k] * w00)));
                f[pl][8 + k] = fmaf((float)b11[k], w11, fmaf((float)b10[k], w10,
                               fmaf((float)b01[k], w01, (float)b00[k] * w00)));
            }
        }
        half8 o0, o1;
        #pragma unroll
        for (int k = 0; k < 8; ++k) {
            o0[k] = (_Float16)(f[0][k]     * f[1][k]     * f[2][k]     * 256.0f);
            o1[k] = (_Float16)(f[0][8 + k] * f[1][8 + k] * f[2][8 + k] * 256.0f);
        }
        *(half8*)&wbase[pl_ * FEAT_STRIDE + hf * 16 + 0] = o0;
        *(half8*)&wbase[pl_ * FEAT_STRIDE + hf * 16 + 8] = o1;
    }

    // a0 reads: wave-private rows written by this wave's own lanes; the
    // compiler orders the aliasing ds_write -> ds_read with lgkmcnt.
    half8 a0[2];
    #pragma unroll
    for (int mt = 0; mt < 2; ++mt)
        a0[mt] = *(const half8*)&wbase[(mt * 16 + l15) * FEAT_STRIDE + quad * 8];

    // per-lane bias/weight scalars
    float b0v[8], b1v[8], w2s[8];
    #pragma unroll
    for (int nt = 0; nt < 8; ++nt) {
        b0v[nt] = b0[nt * 16 + l15] * 4096.0f;
        b1v[nt] = b1[nt * 16 + l15] * 4096.0f;
        w2s[nt] = w2[nt * 16 + l15] * (1.0f / 4096.0f);
    }

    // ================= layer 0 (h0 writes clobber feat region; WAR ordered
    // by lgkmcnt since a0 loads precede in this thread's stream) ============
    #pragma unroll 1
    for (int nt = 0; nt < 8; ++nt) {
        const half8 bfr = *(const half8*)&w0h[(nt * 16 + l15) * NCH + quad * 8];
        f32x4 acc[2];
        #pragma unroll
        for (int mt = 0; mt < 2; ++mt) {
            acc[mt] = (f32x4){0.f, 0.f, 0.f, 0.f};
            acc[mt] = __builtin_amdgcn_mfma_f32_16x16x32_f16(
                a0[mt], bfr, acc[mt], 0, 0, 0);
        }
        #pragma unroll
        for (int mt = 0; mt < 2; ++mt)
            #pragma unroll
            for (int r = 0; r < 4; ++r) {
                const float hval = fmaxf(acc[mt][r] + b0v[nt], 0.0f);
                wbase[(mt * 16 + quad * 4 + r) * H0_STRIDE + nt * 16 + l15]
                    = (_Float16)hval;
            }
    }

    // ================= layer 1 (+ fused layer-2 epilogue) ==================
    half8 a1[2][4];
    #pragma unroll
    for (int mt = 0; mt < 2; ++mt)
        #pragma unroll
        for (int ks = 0; ks < 4; ++ks)
            a1[mt][ks] = *(const half8*)
                &wbase[(mt * 16 + l15) * H0_STRIDE + ks * 32 + quad * 8];

    float part[2][4];
    #pragma unroll
    for (int mt = 0; mt < 2; ++mt)
        #pragma unroll
        for (int r = 0; r < 4; ++r) part[mt][r] = 0.0f;

    #pragma unroll 2
    for (int nt = 0; nt < 8; ++nt) {
        f32x4 acc[2];
        #pragma unroll
        for (int mt = 0; mt < 2; ++mt) acc[mt] = (f32x4){0.f, 0.f, 0.f, 0.f};
        #pragma unroll
        for (int ks = 0; ks < 4; ++ks) {
            const half8 bfr = *(const half8*)
                &w1h[(nt * 16 + l15) * 128 + ks * 32 + quad * 8];
            #pragma unroll
            for (int mt = 0; mt < 2; ++mt)
                acc[mt] = __builtin_amdgcn_mfma_f32_16x16x32_f16(
                    a1[mt][ks], bfr, acc[mt], 0, 0, 0);
        }
        #pragma unroll
        for (int mt = 0; mt < 2; ++mt)
            #pragma unroll
            for (int r = 0; r < 4; ++r)
                part[mt][r] = fmaf(w2s[nt], fmaxf(acc[mt][r] + b1v[nt], 0.0f),
                                   part[mt][r]);
    }

    // reduce across the 16 lanes (l15) of each quad-group
    #pragma unroll
    for (int mt = 0; mt < 2; ++mt)
        #pragma unroll
        for (int r = 0; r < 4; ++r) {
            float s = part[mt][r];
            s += __shfl_xor(s, 1);
            s += __shfl_xor(s, 2);
            s += __shfl_xor(s, 4);
            s += __shfl_xor(s, 8);
            part[mt][r] = s;
        }

    if (l15 == 0) {
        const float bias2 = b2[0];
        const int base = blockIdx.x * 128 + wv * 32;
        #pragma unroll
        for (int mt = 0; mt < 2; ++mt)
            #pragma unroll
            for (int r = 0; r < 4; ++r)
                out[base + mt * 16 + quad * 4 + r] = part[mt][r] + bias2;
    }
}

// ---------------------------------------------------------------------------
// Fallback (ws too small): round-1 fused fp32 kernel on original layout.
// ---------------------------------------------------------------------------
__global__ __launch_bounds__(256) void fused_fallback(
    const float* __restrict__ planes, const float* __restrict__ coords,
    const float* __restrict__ w0, const float* __restrict__ b0,
    const float* __restrict__ w1, const float* __restrict__ b1,
    const float* __restrict__ w2, const float* __restrict__ b2,
    float* __restrict__ out)
{
    const int t = blockIdx.x * 256 + threadIdx.x;
    const int b = t >> 17;
    const float cx = coords[(size_t)t * 3 + 0];
    const float cy = coords[(size_t)t * 3 + 1];
    const float cz = coords[(size_t)t * 3 + 2];
    float feat[NCH];
    #pragma unroll
    for (int p = 0; p < 3; ++p) {
        const float u = (p == 0) ? cx : (p == 1) ? cy : cx;
        const float v = (p == 0) ? cy : cz;
        const float fx = (u + 1.0f) * 0.5f * (RES - 1);
        const float fy = (v + 1.0f) * 0.5f * (RES - 1);
        const float x0f = floorf(fx), y0f = floorf(fy);
        const float wx = fx - x0f, wy = fy - y0f;
        const int x0 = (int)x0f, y0 = (int)y0f;
        const bool vx1 = (x0 + 1) < RES, vy1 = (y0 + 1) < RES;
        const int x1 = vx1 ? x0 + 1 : RES - 1;
        const int y1 = vy1 ? y0 + 1 : RES - 1;
        float w00 = (1.0f - wx) * (1.0f - wy), w01 = wx * (1.0f - wy);
        float w10 = (1.0f - wx) * wy, w11 = wx * wy;
        if (!vx1) { w01 = 0.0f; w11 = 0.0f; }
        if (!vy1) { w10 = 0.0f; w11 = 0.0f; }
        const float* base = planes + (size_t)(b * 3 + p) * NCH * RES * RES;
        const float* p00 = base + (size_t)y0 * RES + x0;
        const float* p01 = base + (size_t)y0 * RES + x1;
        const float* p10 = base + (size_t)y1 * RES + x0;
        const float* p11 = base + (size_t)y1 * RES + x1;
        #pragma unroll
        for (int c = 0; c < NCH; ++c) {
            const size_t off = (size_t)c * RES * RES;
            float s = p00[off] * w00;
            s = fmaf(p01[off], w01, s);
            s = fmaf(p10[off], w10, s);
            s = fmaf(p11[off], w11, s);
            if (p == 0) feat[c] = s; else feat[c] *= s;
        }
    }
    float h0[128];
    #pragma unroll
    for (int g = 0; g < 128; ++g) {
        const float* wr = w0 + g * NCH;
        float aA = b0[g], aB = 0.0f;
        #pragma unroll
        for (int c = 0; c < NCH; c += 2) {
            aA = fmaf(wr[c], feat[c], aA);
            aB = fmaf(wr[c + 1], feat[c + 1], aB);
        }
        h0[g] = fmaxf(aA + aB, 0.0f);
    }
    float o = b2[0];
    for (int g = 0; g < 128; ++g) {
        const float* wr = w1 + g * 128;
        float aA = b1[g], aB = 0.0f, aC = 0.0f, aD = 0.0f;
        #pragma unroll
        for (int h = 0; h < 128; h += 4) {
            aA = fmaf(wr[h], h0[h], aA);
            aB = fmaf(wr[h + 1], h0[h + 1], aB);
            aC = fmaf(wr[h + 2], h0[h + 2], aC);
            aD = fmaf(wr[h + 3], h0[h + 3], aD);
        }
        o = fmaf(fmaxf((aA + aB) + (aC + aD), 0.0f), w2[g], o);
    }
    out[t] = o;
}

// ---------------------------------------------------------------------------
extern "C" void kernel_launch(void* const* d_in, const int* in_sizes, int n_in,
                              void* d_out, int out_size, void* d_ws, size_t ws_size,
                              hipStream_t stream)
{
    const float* trip   = (const float*)d_in[0];
    const float* coords = (const float*)d_in[1];
    const float* w0     = (const float*)d_in[2];
    const float* b0     = (const float*)d_in[3];
    const float* w1     = (const float*)d_in[4];
    const float* b1     = (const float*)d_in[5];
    const float* w2     = (const float*)d_in[6];
    const float* b2     = (const float*)d_in[7];
    float* out = (float*)d_out;

    const size_t planesTBytes = (size_t)NB * 3 * RES * RES * NCH * 2;   // 50331648
    const size_t w0hBytes = 128 * NCH * 2;                              // 8192
    const size_t w1hBytes = 128 * 128 * 2;                              // 32768
    const size_t needed = planesTBytes + w0hBytes + w1hBytes;

    if (ws_size >= needed) {
        _Float16* planesT = (_Float16*)d_ws;
        _Float16* w0h     = (_Float16*)((char*)d_ws + planesTBytes);
        _Float16* w1h     = (_Float16*)((char*)d_ws + planesTBytes + w0hBytes);

        transpose_prep_kernel<<<dim3(RES, NB * 3 + 1), 256, 0, stream>>>(
            trip, w0, w1, planesT, w0h, w1h);
        fused_kernel<<<(NB * NPT) / 128, 256, 0, stream>>>(
            planesT, coords, w0h, w1h, b0, b1, w2, b2, out);
    } else {
        fused_fallback<<<(NB * NPT) / 256, 256, 0, stream>>>(
            trip, coords, w0, b0, w1, b1, w2, b2, out);
    }
}

// Round 9
// 286.598 us; speedup vs baseline: 1.8651x; 1.0336x over previous
//
#include <hip/hip_runtime.h>
#include <hip/hip_bf16.h>
#include <cstddef>

#define RES 256
#define NCH 32
#define NPT 131072   // points per batch
#define NB  4

typedef _Float16 half8 __attribute__((ext_vector_type(8)));
typedef _Float16 half4 __attribute__((ext_vector_type(4)));
typedef float    f32x4 __attribute__((ext_vector_type(4)));

#define FEAT_STRIDE 40    // halves per feat row (32+8 pad, 80B rows, 16B-aligned)
#define H0_STRIDE   136   // halves per h0 row (128+8 pad, 272B rows, 16B-aligned)
#define WAVE_LDS    (32 * H0_STRIDE)   // halves per wave (8704 B)

// ---------------------------------------------------------------------------
// Transpose + fp16 convert + weight prep, one kernel.
// bp 0..11: [bp][c][y][x] f32 -> [bp][y][x][c] f16 (1 row/block).
// bp == 12: convert w0/w1 to fp16 with scaling (w0h = w0*16, w1h = w1).
// (feat scaled x256 at sampling; net h0 scale 4096, undone via w2/4096.)
// ---------------------------------------------------------------------------
__global__ __launch_bounds__(256) void transpose_prep_kernel(
    const float* __restrict__ in,
    const float* __restrict__ w0, const float* __restrict__ w1,
    _Float16* __restrict__ out,
    _Float16* __restrict__ w0h, _Float16* __restrict__ w1h)
{
    const int bp = blockIdx.y;                 // 0..12
    const int t  = threadIdx.x;

    if (bp == 12) {                            // weight-prep blocks
        const int i = blockIdx.x * 256 + t;
        if (i < 128 * NCH)  w0h[i] = (_Float16)(w0[i] * 16.0f);
        if (i < 128 * 128)  w1h[i] = (_Float16)w1[i];
        return;
    }

    __shared__ _Float16 tileh[NCH][RES + 8];   // 16.5 KB
    const int y = blockIdx.x;                  // 0..255

    const float4* src4 = (const float4*)(in + (size_t)bp * NCH * RES * RES);
    const int lane64 = t & 63;
    const int cq     = t >> 6;                 // 0..3
    #pragma unroll
    for (int i = 0; i < 8; ++i) {
        const int c = cq * 8 + i;
        const float4 v = src4[(size_t)c * (RES * RES / 4) + y * (RES / 4) + lane64];
        half4 h = { (_Float16)v.x, (_Float16)v.y, (_Float16)v.z, (_Float16)v.w };
        *(half4*)&tileh[c][lane64 * 4] = h;
    }
    __syncthreads();

    _Float16* dst = out + ((size_t)bp * RES * RES + (size_t)y * RES) * NCH;
    const int x = t;                           // texel 0..255
    #pragma unroll
    for (int cg = 0; cg < 4; ++cg) {
        half8 h;
        #pragma unroll
        for (int k = 0; k < 8; ++k)
            h[k] = tileh[cg * 8 + k][x];
        *(half8*)&dst[(size_t)x * NCH + cg * 8] = h;
    }
}

// ---------------------------------------------------------------------------
// Fused sample + MFMA MLP, ONE WAVE PER BLOCK (64 threads), zero barriers.
// Each block/wave owns 32 points end-to-end and 8.7 KB of LDS (feat rows
// aliased into the low 2.5 KB of the h0 region). LDS/block = 8.7 KB ->
// residency capped by the 16-workgroup/CU HW limit = 16 waves/CU (50%),
// up from ~10 at 256-thread blocks (R8: occupancy was the gather limiter).
// All LDS deps are within-wave; compiler lgkmcnt orders aliasing
// ds_write->ds_read (proven R7/R8). launch_bounds(64,2): VGPR cap >=128
// under the empirical cap rule (R5: cap = 256/min_waves) -- no spill.
// MFMA 16x16x32 f16 layouts (verified m89/m120 + rounds 3/4/6/7):
//   A: lane holds A[m=lane&15][k=quad*8+j]
//   B: lane holds B[k=quad*8+j][n=lane&15] = W[n][k] row-major 8-contig
//   C/D: col n = lane&15, row m = quad*4+reg
// ---------------------------------------------------------------------------
__global__ __launch_bounds__(64, 2) void fused_kernel(
    const _Float16* __restrict__ planesT,   // [12][256][256][32] f16
    const float* __restrict__ coords,
    const _Float16* __restrict__ w0h,       // [128][32]  (x16)
    const _Float16* __restrict__ w1h,       // [128][128]
    const float* __restrict__ b0, const float* __restrict__ b1,
    const float* __restrict__ w2, const float* __restrict__ b2,
    float* __restrict__ out)
{
    __shared__ __align__(16) _Float16 wbase[WAVE_LDS];   // 8.7 KB, wave-private

    const int tid  = threadIdx.x;           // 0..63 (one wave)
    const int l15  = tid & 15;
    const int quad = tid >> 4;

    // ================= phase A: bilinear sample, 2 threads/point ===========
    {
        const int p  = tid >> 1;                    // wave-local point 0..31
        const int hf = tid & 1;                     // channel half
        const int gp = blockIdx.x * 32 + p;
        const int b  = gp >> 17;                    // NPT = 2^17
        const float cx = coords[(size_t)gp * 3 + 0];
        const float cy = coords[(size_t)gp * 3 + 1];
        const float cz = coords[(size_t)gp * 3 + 2];

        float f[3][16];
        #pragma unroll
        for (int pl = 0; pl < 3; ++pl) {
            const float u = (pl == 0) ? cx : (pl == 1) ? cy : cx;
            const float v = (pl == 0) ? cy : cz;

            const float fx = (u + 1.0f) * 0.5f * (RES - 1);
            const float fy = (v + 1.0f) * 0.5f * (RES - 1);
            const float x0f = floorf(fx), y0f = floorf(fy);
            const float wx = fx - x0f, wy = fy - y0f;
            const int x0 = (int)x0f, y0 = (int)y0f;
            const bool vx1 = (x0 + 1) < RES;
            const bool vy1 = (y0 + 1) < RES;
            const int x1 = vx1 ? x0 + 1 : RES - 1;
            const int y1 = vy1 ? y0 + 1 : RES - 1;

            float w00 = (1.0f - wx) * (1.0f - wy);
            float w01 = wx * (1.0f - wy);
            float w10 = (1.0f - wx) * wy;
            float w11 = wx * wy;
            if (!vx1) { w01 = 0.0f; w11 = 0.0f; }
            if (!vy1) { w10 = 0.0f; w11 = 0.0f; }

            const _Float16* base = planesT
                + ((size_t)(b * 3 + pl) * RES * RES) * NCH + hf * 16;

            const half8* p00 = (const half8*)(base + (size_t)(y0 * RES + x0) * NCH);
            const half8* p01 = (const half8*)(base + (size_t)(y0 * RES + x1) * NCH);
            const half8* p10 = (const half8*)(base + (size_t)(y1 * RES + x0) * NCH);
            const half8* p11 = (const half8*)(base + (size_t)(y1 * RES + x1) * NCH);

            const half8 a00 = p00[0], b00 = p00[1];
            const half8 a01 = p01[0], b01 = p01[1];
            const half8 a10 = p10[0], b10 = p10[1];
            const half8 a11 = p11[0], b11 = p11[1];

            #pragma unroll
            for (int k = 0; k < 8; ++k) {
                f[pl][k] = fmaf((float)a11[k], w11, fmaf((float)a10[k], w10,
                           fmaf((float)a01[k], w01, (float)a00[k] * w00)));
                f[pl][8 + k] = fmaf((float)b11[k], w11, fmaf((float)b10[k], w10,
                               fmaf((float)b01[k], w01, (float)b00[k] * w00)));
            }
        }
        half8 o0, o1;
        #pragma unroll
        for (int k = 0; k < 8; ++k) {
            o0[k] = (_Float16)(f[0][k]     * f[1][k]     * f[2][k]     * 256.0f);
            o1[k] = (_Float16)(f[0][8 + k] * f[1][8 + k] * f[2][8 + k] * 256.0f);
        }
        *(half8*)&wbase[p * FEAT_STRIDE + hf * 16 + 0] = o0;
        *(half8*)&wbase[p * FEAT_STRIDE + hf * 16 + 8] = o1;
    }

    // a0 reads: same wave wrote these rows; lgkmcnt orders write->read.
    half8 a0[2];
    #pragma unroll
    for (int mt = 0; mt < 2; ++mt)
        a0[mt] = *(const half8*)&wbase[(mt * 16 + l15) * FEAT_STRIDE + quad * 8];

    // per-lane bias/weight scalars
    float b0v[8], b1v[8], w2s[8];
    #pragma unroll
    for (int nt = 0; nt < 8; ++nt) {
        b0v[nt] = b0[nt * 16 + l15] * 4096.0f;
        b1v[nt] = b1[nt * 16 + l15] * 4096.0f;
        w2s[nt] = w2[nt * 16 + l15] * (1.0f / 4096.0f);
    }

    // ================= layer 0 (h0 writes clobber feat region; WAR ordered
    // by lgkmcnt since a0 loads precede in program order) ===================
    #pragma unroll 1
    for (int nt = 0; nt < 8; ++nt) {
        const half8 bfr = *(const half8*)&w0h[(nt * 16 + l15) * NCH + quad * 8];
        f32x4 acc[2];
        #pragma unroll
        for (int mt = 0; mt < 2; ++mt) {
            acc[mt] = (f32x4){0.f, 0.f, 0.f, 0.f};
            acc[mt] = __builtin_amdgcn_mfma_f32_16x16x32_f16(
                a0[mt], bfr, acc[mt], 0, 0, 0);
        }
        #pragma unroll
        for (int mt = 0; mt < 2; ++mt)
            #pragma unroll
            for (int r = 0; r < 4; ++r) {
                const float hval = fmaxf(acc[mt][r] + b0v[nt], 0.0f);
                wbase[(mt * 16 + quad * 4 + r) * H0_STRIDE + nt * 16 + l15]
                    = (_Float16)hval;
            }
    }

    // ================= layer 1 (+ fused layer-2 epilogue) ==================
    half8 a1[2][4];
    #pragma unroll
    for (int mt = 0; mt < 2; ++mt)
        #pragma unroll
        for (int ks = 0; ks < 4; ++ks)
            a1[mt][ks] = *(const half8*)
                &wbase[(mt * 16 + l15) * H0_STRIDE + ks * 32 + quad * 8];

    float part[2][4];
    #pragma unroll
    for (int mt = 0; mt < 2; ++mt)
        #pragma unroll
        for (int r = 0; r < 4; ++r) part[mt][r] = 0.0f;

    #pragma unroll 2
    for (int nt = 0; nt < 8; ++nt) {
        f32x4 acc[2];
        #pragma unroll
        for (int mt = 0; mt < 2; ++mt) acc[mt] = (f32x4){0.f, 0.f, 0.f, 0.f};
        #pragma unroll
        for (int ks = 0; ks < 4; ++ks) {
            const half8 bfr = *(const half8*)
                &w1h[(nt * 16 + l15) * 128 + ks * 32 + quad * 8];
            #pragma unroll
            for (int mt = 0; mt < 2; ++mt)
                acc[mt] = __builtin_amdgcn_mfma_f32_16x16x32_f16(
                    a1[mt][ks], bfr, acc[mt], 0, 0, 0);
        }
        #pragma unroll
        for (int mt = 0; mt < 2; ++mt)
            #pragma unroll
            for (int r = 0; r < 4; ++r)
                part[mt][r] = fmaf(w2s[nt], fmaxf(acc[mt][r] + b1v[nt], 0.0f),
                                   part[mt][r]);
    }

    // reduce across the 16 lanes (l15) of each quad-group
    #pragma unroll
    for (int mt = 0; mt < 2; ++mt)
        #pragma unroll
        for (int r = 0; r < 4; ++r) {
            float s = part[mt][r];
            s += __shfl_xor(s, 1);
            s += __shfl_xor(s, 2);
            s += __shfl_xor(s, 4);
            s += __shfl_xor(s, 8);
            part[mt][r] = s;
        }

    if (l15 == 0) {
        const float bias2 = b2[0];
        const int base = blockIdx.x * 32;
        #pragma unroll
        for (int mt = 0; mt < 2; ++mt)
            #pragma unroll
            for (int r = 0; r < 4; ++r)
                out[base + mt * 16 + quad * 4 + r] = part[mt][r] + bias2;
    }
}

// ---------------------------------------------------------------------------
// Fallback (ws too small): round-1 fused fp32 kernel on original layout.
// ---------------------------------------------------------------------------
__global__ __launch_bounds__(256) void fused_fallback(
    const float* __restrict__ planes, const float* __restrict__ coords,
    const float* __restrict__ w0, const float* __restrict__ b0,
    const float* __restrict__ w1, const float* __restrict__ b1,
    const float* __restrict__ w2, const float* __restrict__ b2,
    float* __restrict__ out)
{
    const int t = blockIdx.x * 256 + threadIdx.x;
    const int b = t >> 17;
    const float cx = coords[(size_t)t * 3 + 0];
    const float cy = coords[(size_t)t * 3 + 1];
    const float cz = coords[(size_t)t * 3 + 2];
    float feat[NCH];
    #pragma unroll
    for (int p = 0; p < 3; ++p) {
        const float u = (p == 0) ? cx : (p == 1) ? cy : cx;
        const float v = (p == 0) ? cy : cz;
        const float fx = (u + 1.0f) * 0.5f * (RES - 1);
        const float fy = (v + 1.0f) * 0.5f * (RES - 1);
        const float x0f = floorf(fx), y0f = floorf(fy);
        const float wx = fx - x0f, wy = fy - y0f;
        const int x0 = (int)x0f, y0 = (int)y0f;
        const bool vx1 = (x0 + 1) < RES, vy1 = (y0 + 1) < RES;
        const int x1 = vx1 ? x0 + 1 : RES - 1;
        const int y1 = vy1 ? y0 + 1 : RES - 1;
        float w00 = (1.0f - wx) * (1.0f - wy), w01 = wx * (1.0f - wy);
        float w10 = (1.0f - wx) * wy, w11 = wx * wy;
        if (!vx1) { w01 = 0.0f; w11 = 0.0f; }
        if (!vy1) { w10 = 0.0f; w11 = 0.0f; }
        const float* base = planes + (size_t)(b * 3 + p) * NCH * RES * RES;
        const float* p00 = base + (size_t)y0 * RES + x0;
        const float* p01 = base + (size_t)y0 * RES + x1;
        const float* p10 = base + (size_t)y1 * RES + x0;
        const float* p11 = base + (size_t)y1 * RES + x1;
        #pragma unroll
        for (int c = 0; c < NCH; ++c) {
            const size_t off = (size_t)c * RES * RES;
            float s = p00[off] * w00;
            s = fmaf(p01[off], w01, s);
            s = fmaf(p10[off], w10, s);
            s = fmaf(p11[off], w11, s);
            if (p == 0) feat[c] = s; else feat[c] *= s;
        }
    }
    float h0[128];
    #pragma unroll
    for (int g = 0; g < 128; ++g) {
        const float* wr = w0 + g * NCH;
        float aA = b0[g], aB = 0.0f;
        #pragma unroll
        for (int c = 0; c < NCH; c += 2) {
            aA = fmaf(wr[c], feat[c], aA);
            aB = fmaf(wr[c + 1], feat[c + 1], aB);
        }
        h0[g] = fmaxf(aA + aB, 0.0f);
    }
    float o = b2[0];
    for (int g = 0; g < 128; ++g) {
        const float* wr = w1 + g * 128;
        float aA = b1[g], aB = 0.0f, aC = 0.0f, aD = 0.0f;
        #pragma unroll
        for (int h = 0; h < 128; h += 4) {
            aA = fmaf(wr[h], h0[h], aA);
            aB = fmaf(wr[h + 1], h0[h + 1], aB);
            aC = fmaf(wr[h + 2], h0[h + 2], aC);
            aD = fmaf(wr[h + 3], h0[h + 3], aD);
        }
        o = fmaf(fmaxf((aA + aB) + (aC + aD), 0.0f), w2[g], o);
    }
    out[t] = o;
}

// ---------------------------------------------------------------------------
extern "C" void kernel_launch(void* const* d_in, const int* in_sizes, int n_in,
                              void* d_out, int out_size, void* d_ws, size_t ws_size,
                              hipStream_t stream)
{
    const float* trip   = (const float*)d_in[0];
    const float* coords = (const float*)d_in[1];
    const float* w0     = (const float*)d_in[2];
    const float* b0     = (const float*)d_in[3];
    const float* w1     = (const float*)d_in[4];
    const float* b1     = (const float*)d_in[5];
    const float* w2     = (const float*)d_in[6];
    const float* b2     = (const float*)d_in[7];
    float* out = (float*)d_out;

    const size_t planesTBytes = (size_t)NB * 3 * RES * RES * NCH * 2;   // 50331648
    const size_t w0hBytes = 128 * NCH * 2;                              // 8192
    const size_t w1hBytes = 128 * 128 * 2;                              // 32768
    const size_t needed = planesTBytes + w0hBytes + w1hBytes;

    if (ws_size >= needed) {
        _Float16* planesT = (_Float16*)d_ws;
        _Float16* w0h     = (_Float16*)((char*)d_ws + planesTBytes);
        _Float16* w1h     = (_Float16*)((char*)d_ws + planesTBytes + w0hBytes);

        transpose_prep_kernel<<<dim3(RES, NB * 3 + 1), 256, 0, stream>>>(
            trip, w0, w1, planesT, w0h, w1h);
        fused_kernel<<<(NB * NPT) / 32, 64, 0, stream>>>(
            planesT, coords, w0h, w1h, b0, b1, w2, b2, out);
    } else {
        fused_fallback<<<(NB * NPT) / 256, 256, 0, stream>>>(
            trip, coords, w0, b0, w1, b1, w2, b2, out);
    }
}